// Round 8
// baseline (266.790 us; speedup 1.0000x reference)
//
#include <hip/hip_runtime.h>

#define TE 64
#define THREADS 256
#define XS 136         // u16 LDS stride per row: 128 + 8 pad (conflict-free)
#define T_SM 0.05f
#define MARGIN_FAST 2.5e-3f  // fp16-Y raw err max ~1.7e-3 (measured 5sigma); 1.5x headroom
#define MARGIN_FB   1e-3f

typedef short s8v __attribute__((ext_vector_type(8)));    // 8 bf16 = 4 VGPRs (MFMA A/B frag)
typedef float f16v __attribute__((ext_vector_type(16)));  // 32x32 C/D frag
typedef unsigned short u16;

__device__ __forceinline__ u16 f2bf(float x) {            // fp32 -> bf16 RNE
    union { float f; unsigned u; } v; v.f = x;
    return (u16)((v.u + 0x7FFFu + ((v.u >> 16) & 1u)) >> 16);
}
__device__ __forceinline__ float bf2f(u16 h) {
    union { unsigned u; float f; } v; v.u = ((unsigned)h) << 16;
    return v.f;
}

// ---- W1 [256,256] f32 -> bf16 hi/lo, LANE-MAJOR B-tile layout ----
// slot(g,p) = (g*256 + p)*16, hi at j=0..7, lo at j=8..15  (g = k>>3, p = out col).
// A B-frag load (fixed g, lanes p..p+31) is lane-stride 32 B -> contiguous 1 KB.
__global__ void prep_kernel(const float* __restrict__ W1, u16* __restrict__ w1t,
                            int* __restrict__ count) {
    int t = blockIdx.x * 256 + threadIdx.x;
    if (t == 0) *count = 0;
    if (t < 65536) {
        int n = t & 255, k = t >> 8;
        float w = W1[k * 256 + n];
        u16 h = f2bf(w);
        u16 l = f2bf(w - bf2f(h));
        int g = k >> 3, j = k & 7;
        int slot = (g * 256 + n) * 16;
        w1t[slot + j] = h;
        w1t[slot + j + 8] = l;
    }
}

// ============================ FAST PATH ============================
// Dense GEMM: Y[n][0:256]=emb[n]@W1[0:128,:]+b1 (b1 FOLDED into Yr half),
//             Y[n][256:512]=emb[n]@W1[128:,:].
// R8: REVERT launch_bounds (256,3)->(256,2). True reg footprint ~224 (96 arch + 128
// acc on unified file); (256,3)'s 170-reg budget forced ~50-reg spill (R6/R7 regression).
// At 224 regs VGPRs cap occupancy at 2 waves/SIMD regardless of LDS.
__global__ __launch_bounds__(THREADS, 2)
void gemm_y_kernel(const float* __restrict__ emb, const u16* __restrict__ w1t,
                   const float* __restrict__ b1, _Float16* __restrict__ Y, int Nn)
{
    __shared__ u16 x_hi[TE * XS];
    __shared__ u16 x_lo[TE * XS];
    __shared__ _Float16 ysc[4][16][136];   // per-wave C-restage scratch (17.4 KB)

    const int tid  = threadIdx.x;
    const int base = blockIdx.x * TE;
    const int lane = tid & 63;
    const int wv   = tid >> 6;
    const int l31  = lane & 31;
    const int q8   = lane >> 5;
    const int ge   = tid >> 5;
    const int gseg = tid & 31;

    #pragma unroll
    for (int q = 0; q < 8; ++q) {
        int node = base + ge + 8 * q;
        if (node >= Nn) node = Nn - 1;
        float4 v = ((const float4*)(emb + (size_t)node * 128))[gseg];
        u16 h0 = f2bf(v.x), h1 = f2bf(v.y), h2 = f2bf(v.z), h3 = f2bf(v.w);
        u16 l0 = f2bf(v.x - bf2f(h0)), l1 = f2bf(v.y - bf2f(h1));
        u16 l2 = f2bf(v.z - bf2f(h2)), l3 = f2bf(v.w - bf2f(h3));
        int off = (ge + 8 * q) * XS + gseg * 4;
        *(uint2*)&x_hi[off] = make_uint2((unsigned)h0 | ((unsigned)h1 << 16),
                                         (unsigned)h2 | ((unsigned)h3 << 16));
        *(uint2*)&x_lo[off] = make_uint2((unsigned)l0 | ((unsigned)l1 << 16),
                                         (unsigned)l2 | ((unsigned)l3 << 16));
    }
    __syncthreads();

    f16v acc[2][4];
    #pragma unroll
    for (int mt = 0; mt < 2; ++mt)
        #pragma unroll
        for (int nt = 0; nt < 4; ++nt)
            acc[mt][nt] = (f16v)0.f;

    const int arow0 = l31 * XS;
    const int arow1 = (32 + l31) * XS;
    const u16* bb[4];
    float b1v[4];
    #pragma unroll
    for (int nt = 0; nt < 4; ++nt) {
        int ncol = wv * 128 + nt * 32 + l31;          // 0..511
        int p = ncol & 255;
        int gbase = (ncol >> 8) * 16;                 // Yr: g0..15, Yc: g16..31
        bb[nt] = w1t + ((size_t)(gbase + q8) * 256 + p) * 16;
        b1v[nt] = (ncol < 256) ? b1[ncol] : 0.f;      // fold b1 into Yr half only
    }

    #pragma unroll
    for (int sl = 0; sl < 8; ++sl) {                  // K=128 in 8 ksteps of 16
        const int aoff = 16 * sl + 8 * q8;
        s8v ah0 = *(const s8v*)&x_hi[arow0 + aoff];
        s8v ah1 = *(const s8v*)&x_hi[arow1 + aoff];
        s8v al0 = *(const s8v*)&x_lo[arow0 + aoff];
        s8v al1 = *(const s8v*)&x_lo[arow1 + aoff];
        #pragma unroll
        for (int nt = 0; nt < 4; ++nt) {
            const u16* bp = bb[nt] + sl * 8192;       // g advances by 2 per sl
            s8v bh = *(const s8v*)bp;
            s8v bl = *(const s8v*)(bp + 8);
            acc[0][nt] = __builtin_amdgcn_mfma_f32_32x32x16_bf16(ah0, bh, acc[0][nt], 0, 0, 0);
            acc[0][nt] = __builtin_amdgcn_mfma_f32_32x32x16_bf16(ah0, bl, acc[0][nt], 0, 0, 0);
            acc[0][nt] = __builtin_amdgcn_mfma_f32_32x32x16_bf16(al0, bh, acc[0][nt], 0, 0, 0);
            acc[1][nt] = __builtin_amdgcn_mfma_f32_32x32x16_bf16(ah1, bh, acc[1][nt], 0, 0, 0);
            acc[1][nt] = __builtin_amdgcn_mfma_f32_32x32x16_bf16(ah1, bl, acc[1][nt], 0, 0, 0);
            acc[1][nt] = __builtin_amdgcn_mfma_f32_32x32x16_bf16(al1, bh, acc[1][nt], 0, 0, 0);
        }
    }

    // epilogue: per-wave LDS restage in 16-row sub-passes -> coalesced uint4 stores.
    const bool full = (base + TE <= Nn);
    const int rr = lane >> 4;          // 0..3
    const int cc = (lane & 15) * 8;    // 0..120
    #pragma unroll
    for (int mt = 0; mt < 2; ++mt) {
        #pragma unroll
        for (int half = 0; half < 2; ++half) {
            #pragma unroll
            for (int r8 = 0; r8 < 8; ++r8) {
                int r = half * 8 + r8;
                int srl = (r & 3) + 8 * (r8 >> 2) + 4 * q8;   // 0..15 within sub-pass
                #pragma unroll
                for (int nt = 0; nt < 4; ++nt)
                    ysc[wv][srl][nt * 32 + l31] = (_Float16)(acc[mt][nt][r] + b1v[nt]);
            }
            #pragma unroll
            for (int it = 0; it < 4; ++it) {
                int row16 = 4 * it + rr;                      // 0..15
                int node = base + mt * 32 + half * 16 + row16;
                uint4 v = *(const uint4*)&ysc[wv][row16][cc];
                if (full || node < Nn)
                    *(uint4*)(Y + (size_t)node * 512 + wv * 128 + cc) = v;
            }
        }
    }
}

// Edge pass: raw(e) = relu(Yr[row]+Yc[col]) . W2 + b2   (b1 pre-folded into Yr).
// INSTRUMENTATION (R8): range-partitioned quarters again (reveal threshold ~26 us)
// to expose gemm_y / fixup durations + VGPR counts by name. Known cost ~16 us.
__global__ __launch_bounds__(256, 8)
void edge_kernel(const _Float16* __restrict__ Y, const int* __restrict__ ei,
                 const float* __restrict__ W2, const float* __restrict__ b2p,
                 float* __restrict__ out, int* __restrict__ count,
                 int* __restrict__ list, int cap, int E, int estart, int eend)
{
    const int tid  = threadIdx.x;
    const int lane = tid & 63;
    const int l31  = tid & 31;
    const int q8   = (tid & 63) >> 5;
    const int l7   = lane & 7;
    const int gw   = (blockIdx.x * 256 + tid) >> 6;
    const int nw   = (gridDim.x * 256) >> 6;

    float w2v[8];
    #pragma unroll
    for (int j = 0; j < 8; ++j) w2v[j] = W2[8 * l31 + j];
    const float b2s = b2p[0];

    const int ecnt = eend - estart;
    const int ngrp = (ecnt + 7) >> 3;          // 8 edges per group

    int rv = 0, cv = 0;
    int myr[4], myc[4];
    if (gw < ngrp) {
        int ib = estart + 8 * gw + l7; if (ib >= eend) ib = eend - 1;
        rv = ei[ib]; cv = ei[E + ib];
    }
    #pragma unroll
    for (int k = 0; k < 4; ++k) {
        myr[k] = __shfl(rv, 2 * k + q8);    // half q8 handles edge 2k+q8
        myc[k] = __shfl(cv, 2 * k + q8);
    }

    for (int g = gw; g < ngrp; g += nw) {
        const int gn = g + nw;

        union U { uint4 u; _Float16 h[8]; };
        U yr[4], yc[4];
        #pragma unroll
        for (int k = 0; k < 4; ++k) {
            yr[k].u = *(const uint4*)(Y + (size_t)myr[k] * 512 + 8 * l31);
            yc[k].u = *(const uint4*)(Y + (size_t)myc[k] * 512 + 256 + 8 * l31);
        }

        // prefetch next group's indices (lands under the compute below)
        if (gn < ngrp) {
            int ib = estart + 8 * gn + l7; if (ib >= eend) ib = eend - 1;
            rv = ei[ib]; cv = ei[E + ib];
        }

        #pragma unroll
        for (int k = 0; k < 4; ++k) {
            const int e = estart + 8 * g + 2 * k + q8;
            float p = 0.f;
            #pragma unroll
            for (int j = 0; j < 8; ++j) {
                float h = (float)yr[k].h[j] + (float)yc[k].h[j];   // b1 already in Yr
                p += (h > 0.f ? h : 0.f) * w2v[j];
            }
            p += __shfl_xor(p, 1);  p += __shfl_xor(p, 2);  p += __shfl_xor(p, 4);
            p += __shfl_xor(p, 8);  p += __shfl_xor(p, 16);   // stays within 32-lane half
            if (l31 == 0 && e < eend) {
                float raw = p + b2s;
                out[e] = (raw < T_SM) ? 0.f : raw;
                if (fabsf(raw - T_SM) < MARGIN_FAST) {
                    int pos = atomicAdd(count, 1);
                    if (pos < cap) list[pos] = e;
                }
            }
        }

        #pragma unroll
        for (int k = 0; k < 4; ++k) {
            myr[k] = __shfl(rv, 2 * k + q8);
            myc[k] = __shfl(cv, 2 * k + q8);
        }
    }
}

// ============================ FALLBACK PATH (R5, proven 475 us) ============================
__global__ __launch_bounds__(THREADS, 3)
void linkmlp_mfma(const float* __restrict__ emb, const int* __restrict__ ei,
                  const u16* __restrict__ w1t, const float* __restrict__ b1,
                  const float* __restrict__ W2, const float* __restrict__ b2p,
                  float* __restrict__ out, int* __restrict__ count,
                  int* __restrict__ list, int cap, int E)
{
    __shared__ u16 x_hi[TE * XS];
    __shared__ u16 x_lo[TE * XS];
    __shared__ float red[4][TE];
    __shared__ int s_idx[2][TE];

    const int tid  = threadIdx.x;
    const int base = blockIdx.x * TE;
    const int lane = tid & 63;
    const int wv   = tid >> 6;
    const int l31  = lane & 31;
    const int q8   = lane >> 5;
    const int ge   = tid >> 5;
    const int gseg = tid & 31;

    if (tid < TE) { int e = base + tid; s_idx[0][tid] = (e < E) ? ei[e] : 0; }
    else if (tid < 2 * TE) { int t2 = tid - TE; int e = base + t2; s_idx[1][t2] = (e < E) ? ei[E + e] : 0; }
    __syncthreads();

    float b1v[2], w2v[2];
    #pragma unroll
    for (int nt = 0; nt < 2; ++nt) {
        int c = wv * 64 + nt * 32 + l31;
        b1v[nt] = b1[c];
        w2v[nt] = W2[c];
    }
    const float b2s = b2p[0];

    f16v acc[2][2];
    #pragma unroll
    for (int mt = 0; mt < 2; ++mt)
        #pragma unroll
        for (int nt = 0; nt < 2; ++nt)
            acc[mt][nt] = (f16v)0.f;

    float4 gv[8];
    auto issue_gather = [&](int half) {
        #pragma unroll
        for (int q = 0; q < 8; ++q) {
            int node = s_idx[half][ge + 8 * q];
            gv[q] = ((const float4*)(emb + (size_t)node * 128))[gseg];
        }
    };
    auto write_gather = [&]() {
        #pragma unroll
        for (int q = 0; q < 8; ++q) {
            float4 v = gv[q];
            u16 h0 = f2bf(v.x), h1 = f2bf(v.y), h2 = f2bf(v.z), h3 = f2bf(v.w);
            u16 l0 = f2bf(v.x - bf2f(h0)), l1 = f2bf(v.y - bf2f(h1));
            u16 l2 = f2bf(v.z - bf2f(h2)), l3 = f2bf(v.w - bf2f(h3));
            int off = (ge + 8 * q) * XS + gseg * 4;
            *(uint2*)&x_hi[off] = make_uint2((unsigned)h0 | ((unsigned)h1 << 16),
                                             (unsigned)h2 | ((unsigned)h3 << 16));
            *(uint2*)&x_lo[off] = make_uint2((unsigned)l0 | ((unsigned)l1 << 16),
                                             (unsigned)l2 | ((unsigned)l3 << 16));
        }
    };

    issue_gather(0);
    write_gather();
    __syncthreads();

    #pragma unroll
    for (int half = 0; half < 2; ++half) {
        const int arow0 = l31 * XS;
        const int arow1 = (32 + l31) * XS;
        // lane-major w1t: slot(g,p) = (g*256+p)*16; p0 = wv*64+l31, p1 = p0+32; g = half*16+q8+2sl
        const u16* bbase0 = w1t + ((size_t)(half * 16 + q8) * 256 + wv * 64 + l31) * 16;
        const u16* bbase1 = bbase0 + 32 * 16;
        if (half == 0) issue_gather(1);

        auto kstep = [&](int sl) {
            const int aoff = 16 * sl + 8 * q8;
            s8v ah0 = *(const s8v*)&x_hi[arow0 + aoff];
            s8v ah1 = *(const s8v*)&x_hi[arow1 + aoff];
            s8v al0 = *(const s8v*)&x_lo[arow0 + aoff];
            s8v al1 = *(const s8v*)&x_lo[arow1 + aoff];
            const u16* bp0 = bbase0 + sl * 8192;
            const u16* bp1 = bbase1 + sl * 8192;
            s8v bh0 = *(const s8v*)bp0;  s8v bl0 = *(const s8v*)(bp0 + 8);
            s8v bh1 = *(const s8v*)bp1;  s8v bl1 = *(const s8v*)(bp1 + 8);
            acc[0][0] = __builtin_amdgcn_mfma_f32_32x32x16_bf16(ah0, bh0, acc[0][0], 0, 0, 0);
            acc[0][0] = __builtin_amdgcn_mfma_f32_32x32x16_bf16(ah0, bl0, acc[0][0], 0, 0, 0);
            acc[0][0] = __builtin_amdgcn_mfma_f32_32x32x16_bf16(al0, bh0, acc[0][0], 0, 0, 0);
            acc[1][0] = __builtin_amdgcn_mfma_f32_32x32x16_bf16(ah1, bh0, acc[1][0], 0, 0, 0);
            acc[1][0] = __builtin_amdgcn_mfma_f32_32x32x16_bf16(ah1, bl0, acc[1][0], 0, 0, 0);
            acc[1][0] = __builtin_amdgcn_mfma_f32_32x32x16_bf16(al1, bh0, acc[1][0], 0, 0, 0);
            acc[0][1] = __builtin_amdgcn_mfma_f32_32x32x16_bf16(ah0, bh1, acc[0][1], 0, 0, 0);
            acc[0][1] = __builtin_amdgcn_mfma_f32_32x32x16_bf16(ah0, bl1, acc[0][1], 0, 0, 0);
            acc[0][1] = __builtin_amdgcn_mfma_f32_32x32x16_bf16(al0, bh1, acc[0][1], 0, 0, 0);
            acc[1][1] = __builtin_amdgcn_mfma_f32_32x32x16_bf16(ah1, bh1, acc[1][1], 0, 0, 0);
            acc[1][1] = __builtin_amdgcn_mfma_f32_32x32x16_bf16(ah1, bl1, acc[1][1], 0, 0, 0);
            acc[1][1] = __builtin_amdgcn_mfma_f32_32x32x16_bf16(al1, bh1, acc[1][1], 0, 0, 0);
        };

        kstep(0); kstep(1); kstep(2); kstep(3);
        kstep(4); kstep(5); kstep(6); kstep(7);

        if (half == 0) {
            __syncthreads();
            write_gather();
            __syncthreads();
        }
    }

    #pragma unroll
    for (int mt = 0; mt < 2; ++mt) {
        #pragma unroll
        for (int r = 0; r < 16; ++r) {
            float h0 = acc[mt][0][r] + b1v[0];
            float h1 = acc[mt][1][r] + b1v[1];
            float pp = (h0 > 0.f ? h0 : 0.f) * w2v[0] + (h1 > 0.f ? h1 : 0.f) * w2v[1];
            pp += __shfl_xor(pp, 1);  pp += __shfl_xor(pp, 2);
            pp += __shfl_xor(pp, 4);  pp += __shfl_xor(pp, 8);
            pp += __shfl_xor(pp, 16);
            if (l31 == 0)
                red[wv][mt * 32 + (r & 3) + 8 * (r >> 2) + 4 * q8] = pp;
        }
    }
    __syncthreads();

    if (tid < TE) {
        int eg = base + tid;
        if (eg < E) {
            float raw = red[0][tid] + red[1][tid] + red[2][tid] + red[3][tid] + b2s;
            out[eg] = (raw < T_SM) ? 0.f : raw;
            if (fabsf(raw - T_SM) < MARGIN_FB) {
                int pos = atomicAdd(count, 1);
                if (pos < cap) list[pos] = eg;
            }
        }
    }
}

// ---- exact fp32 recompute of near-threshold edges ----
// 4 edges per wave; shared W1 stream amortized over 4 edges.
__global__ __launch_bounds__(256, 4)
void fixup_kernel(const float* __restrict__ emb, const int* __restrict__ ei,
                  const float* __restrict__ W1, const float* __restrict__ b1,
                  const float* __restrict__ W2, const float* __restrict__ b2p,
                  const int* __restrict__ count, const int* __restrict__ list,
                  float* __restrict__ out, int E, int cap)
{
    int cnt = *count; if (cnt > cap) cnt = cap;
    const int lane = threadIdx.x & 63;
    const int gw = (blockIdx.x * 256 + threadIdx.x) >> 6;
    const int nw = (gridDim.x * 256) >> 6;
    const int nbatch = (cnt + 3) >> 2;

    float b1l[4], w2l[4];
    #pragma unroll
    for (int c = 0; c < 4; ++c) {
        b1l[c] = b1[lane + 64 * c];
        w2l[c] = W2[lane + 64 * c];
    }
    const float b2s = b2p[0];

    for (int b = gw; b < nbatch; b += nw) {
        int e[4]; float4 xv[4];
        #pragma unroll
        for (int i = 0; i < 4; ++i) {
            int idx = 4 * b + i;
            e[i] = (idx < cnt) ? list[idx] : list[0];   // pad: benign duplicate recompute
            int rn = ei[e[i]], cn = ei[E + e[i]];
            const float* src = (lane < 32) ? emb + (size_t)rn * 128 + lane * 4
                                           : emb + (size_t)cn * 128 + (lane - 32) * 4;
            xv[i] = *(const float4*)src;
        }
        float hacc[4][4] = {{0.f,0.f,0.f,0.f},{0.f,0.f,0.f,0.f},
                            {0.f,0.f,0.f,0.f},{0.f,0.f,0.f,0.f}};
        for (int k0 = 0; k0 < 256; k0 += 8) {
            int sl = k0 >> 2;
            float w[8][4];
            #pragma unroll
            for (int kk = 0; kk < 8; ++kk)
                #pragma unroll
                for (int c = 0; c < 4; ++c)
                    w[kk][c] = W1[(k0 + kk) * 256 + lane + 64 * c];
            #pragma unroll
            for (int i = 0; i < 4; ++i) {
                float x[8];
                x[0] = __shfl(xv[i].x, sl);     x[1] = __shfl(xv[i].y, sl);
                x[2] = __shfl(xv[i].z, sl);     x[3] = __shfl(xv[i].w, sl);
                x[4] = __shfl(xv[i].x, sl + 1); x[5] = __shfl(xv[i].y, sl + 1);
                x[6] = __shfl(xv[i].z, sl + 1); x[7] = __shfl(xv[i].w, sl + 1);
                #pragma unroll
                for (int c = 0; c < 4; ++c) {
                    float s = hacc[i][c];
                    #pragma unroll
                    for (int kk = 0; kk < 8; ++kk)
                        s += x[kk] * w[kk][c];
                    hacc[i][c] = s;
                }
            }
        }
        #pragma unroll
        for (int i = 0; i < 4; ++i) {
            float p = 0.f;
            #pragma unroll
            for (int c = 0; c < 4; ++c) {
                float h = hacc[i][c] + b1l[c];
                p += (h > 0.f ? h : 0.f) * w2l[c];
            }
            p += __shfl_xor(p, 1);  p += __shfl_xor(p, 2);  p += __shfl_xor(p, 4);
            p += __shfl_xor(p, 8);  p += __shfl_xor(p, 16); p += __shfl_xor(p, 32);
            if (lane == 0) {
                float raw = p + b2s;
                out[e[i]] = (raw < T_SM) ? 0.f : raw;
            }
        }
    }
}

extern "C" void kernel_launch(void* const* d_in, const int* in_sizes, int n_in,
                              void* d_out, int out_size, void* d_ws, size_t ws_size,
                              hipStream_t stream) {
    const float* emb = (const float*)d_in[0];
    const int*   ei  = (const int*)  d_in[1];
    const float* W1  = (const float*)d_in[2];
    const float* b1  = (const float*)d_in[3];
    const float* W2  = (const float*)d_in[4];
    const float* b2  = (const float*)d_in[5];
    float* out = (float*)d_out;
    const int E  = out_size;
    const int Nn = in_sizes[0] / 128;

    const size_t yBytes = (size_t)Nn * 512 * sizeof(_Float16);   // 102.4 MB @ N=100000
    const size_t fastNeed = yBytes + 262144 + 64 + 65536;

    if (ws_size >= fastNeed) {
        // fast path: factorized Y-table
        _Float16* Y = (_Float16*)d_ws;
        u16* w1t   = (u16*)((char*)d_ws + yBytes);
        int* count = (int*)((char*)d_ws + yBytes + 262144);
        int* list  = (int*)((char*)d_ws + yBytes + 262208);
        int cap = (int)((ws_size - (yBytes + 262208)) / 4);
        if (cap > E) cap = E;

        hipLaunchKernelGGL(prep_kernel, dim3(256), dim3(256), 0, stream, W1, w1t, count);
        hipLaunchKernelGGL(gemm_y_kernel, dim3((Nn + TE - 1) / TE), dim3(THREADS), 0, stream,
                           emb, w1t, b1, Y, Nn);
        // 4 quarter-dispatches (instrumentation: lowers top-5 reveal threshold to ~26 us)
        int eq = ((E + 31) >> 5) << 3;      // quarter size, multiple of 8
        for (int d = 0; d < 4; ++d) {
            int es = d * eq;
            int ee = (d == 3) ? E : (es + eq);
            if (es >= E) break;
            if (ee > E) ee = E;
            hipLaunchKernelGGL(edge_kernel, dim3(1024), dim3(256), 0, stream,
                               Y, ei, W2, b2, out, count, list, cap, E, es, ee);
        }
        hipLaunchKernelGGL(fixup_kernel, dim3(1024), dim3(256), 0, stream,
                           emb, ei, W1, b1, W2, b2, count, list, out, E, cap);
    } else {
        // fallback: R5 fused edge-GEMM (proven)
        u16* w1t   = (u16*)d_ws;
        int* count = (int*)((char*)d_ws + 262144);
        int* list  = (int*)((char*)d_ws + 262208);
        long avail = (long)ws_size - 262208;
        int cap = (avail > 4) ? (int)(avail / 4) : 0;
        if (cap > E) cap = E;

        hipLaunchKernelGGL(prep_kernel, dim3(256), dim3(256), 0, stream, W1, w1t, count);
        hipLaunchKernelGGL(linkmlp_mfma, dim3((E + TE - 1) / TE), dim3(THREADS), 0, stream,
                           emb, ei, w1t, b1, W2, b2, out, count, list, cap, E);
        hipLaunchKernelGGL(fixup_kernel, dim3(128), dim3(256), 0, stream,
                           emb, ei, W1, b1, W2, b2, count, list, out, E, cap);
    }
}

// Round 9
// 250.675 us; speedup vs baseline: 1.0643x; 1.0643x over previous
//
#include <hip/hip_runtime.h>

#define TE 64
#define THREADS 256
#define XS 136         // u16 LDS stride per row: 128 + 8 pad (conflict-free)
#define T_SM 0.05f
#define MARGIN_FAST 2.5e-3f  // fp16-Y raw err max ~1.7e-3 (measured 5sigma); 1.5x headroom
#define MARGIN_FB   1e-3f

typedef short s8v __attribute__((ext_vector_type(8)));    // 8 bf16 = 4 VGPRs (MFMA A/B frag)
typedef float f16v __attribute__((ext_vector_type(16)));  // 32x32 C/D frag
typedef unsigned short u16;

__device__ __forceinline__ u16 f2bf(float x) {            // fp32 -> bf16 RNE
    union { float f; unsigned u; } v; v.f = x;
    return (u16)((v.u + 0x7FFFu + ((v.u >> 16) & 1u)) >> 16);
}
__device__ __forceinline__ float bf2f(u16 h) {
    union { unsigned u; float f; } v; v.u = ((unsigned)h) << 16;
    return v.f;
}

// ---- W1 [256,256] f32 -> bf16 hi/lo, LANE-MAJOR B-tile layout ----
// slot(g,p) = (g*256 + p)*16, hi at j=0..7, lo at j=8..15  (g = k>>3, p = out col).
// A B-frag load (fixed g, lanes p..p+31) is lane-stride 32 B -> contiguous 1 KB.
__global__ void prep_kernel(const float* __restrict__ W1, u16* __restrict__ w1t,
                            int* __restrict__ count) {
    int t = blockIdx.x * 256 + threadIdx.x;
    if (t == 0) *count = 0;
    if (t < 65536) {
        int n = t & 255, k = t >> 8;
        float w = W1[k * 256 + n];
        u16 h = f2bf(w);
        u16 l = f2bf(w - bf2f(h));
        int g = k >> 3, j = k & 7;
        int slot = (g * 256 + n) * 16;
        w1t[slot + j] = h;
        w1t[slot + j + 8] = l;
    }
}

// ============================ FAST PATH ============================
// Dense GEMM: Y[n][0:256]=emb[n]@W1[0:128,:]+b1 (b1 FOLDED into Yr half),
//             Y[n][256:512]=emb[n]@W1[128:,:].
// R9: epilogue reverted to R4 scalar stores (proven 65-69 us). R5-R8's LDS restage
// was a +15 us regression (400K bank-conflict cycles; R8 rocprof) masked by fixup's win.
// Occupancy fixed at 2 waves/SIMD by 128 acc regs + ~96 arch -> LDS is not the cap.
__global__ __launch_bounds__(THREADS, 2)
void gemm_y_kernel(const float* __restrict__ emb, const u16* __restrict__ w1t,
                   const float* __restrict__ b1, _Float16* __restrict__ Y, int Nn)
{
    __shared__ u16 x_hi[TE * XS];
    __shared__ u16 x_lo[TE * XS];

    const int tid  = threadIdx.x;
    const int base = blockIdx.x * TE;
    const int lane = tid & 63;
    const int wv   = tid >> 6;
    const int l31  = lane & 31;
    const int q8   = lane >> 5;
    const int ge   = tid >> 5;
    const int gseg = tid & 31;

    #pragma unroll
    for (int q = 0; q < 8; ++q) {
        int node = base + ge + 8 * q;
        if (node >= Nn) node = Nn - 1;
        float4 v = ((const float4*)(emb + (size_t)node * 128))[gseg];
        u16 h0 = f2bf(v.x), h1 = f2bf(v.y), h2 = f2bf(v.z), h3 = f2bf(v.w);
        u16 l0 = f2bf(v.x - bf2f(h0)), l1 = f2bf(v.y - bf2f(h1));
        u16 l2 = f2bf(v.z - bf2f(h2)), l3 = f2bf(v.w - bf2f(h3));
        int off = (ge + 8 * q) * XS + gseg * 4;
        *(uint2*)&x_hi[off] = make_uint2((unsigned)h0 | ((unsigned)h1 << 16),
                                         (unsigned)h2 | ((unsigned)h3 << 16));
        *(uint2*)&x_lo[off] = make_uint2((unsigned)l0 | ((unsigned)l1 << 16),
                                         (unsigned)l2 | ((unsigned)l3 << 16));
    }
    __syncthreads();

    f16v acc[2][4];
    #pragma unroll
    for (int mt = 0; mt < 2; ++mt)
        #pragma unroll
        for (int nt = 0; nt < 4; ++nt)
            acc[mt][nt] = (f16v)0.f;

    const int arow0 = l31 * XS;
    const int arow1 = (32 + l31) * XS;
    const u16* bb[4];
    float b1v[4];
    #pragma unroll
    for (int nt = 0; nt < 4; ++nt) {
        int ncol = wv * 128 + nt * 32 + l31;          // 0..511
        int p = ncol & 255;
        int gbase = (ncol >> 8) * 16;                 // Yr: g0..15, Yc: g16..31
        bb[nt] = w1t + ((size_t)(gbase + q8) * 256 + p) * 16;
        b1v[nt] = (ncol < 256) ? b1[ncol] : 0.f;      // fold b1 into Yr half only
    }

    #pragma unroll
    for (int sl = 0; sl < 8; ++sl) {                  // K=128 in 8 ksteps of 16
        const int aoff = 16 * sl + 8 * q8;
        s8v ah0 = *(const s8v*)&x_hi[arow0 + aoff];
        s8v ah1 = *(const s8v*)&x_hi[arow1 + aoff];
        s8v al0 = *(const s8v*)&x_lo[arow0 + aoff];
        s8v al1 = *(const s8v*)&x_lo[arow1 + aoff];
        #pragma unroll
        for (int nt = 0; nt < 4; ++nt) {
            const u16* bp = bb[nt] + sl * 8192;       // g advances by 2 per sl
            s8v bh = *(const s8v*)bp;
            s8v bl = *(const s8v*)(bp + 8);
            acc[0][nt] = __builtin_amdgcn_mfma_f32_32x32x16_bf16(ah0, bh, acc[0][nt], 0, 0, 0);
            acc[0][nt] = __builtin_amdgcn_mfma_f32_32x32x16_bf16(ah0, bl, acc[0][nt], 0, 0, 0);
            acc[0][nt] = __builtin_amdgcn_mfma_f32_32x32x16_bf16(al0, bh, acc[0][nt], 0, 0, 0);
            acc[1][nt] = __builtin_amdgcn_mfma_f32_32x32x16_bf16(ah1, bh, acc[1][nt], 0, 0, 0);
            acc[1][nt] = __builtin_amdgcn_mfma_f32_32x32x16_bf16(ah1, bl, acc[1][nt], 0, 0, 0);
            acc[1][nt] = __builtin_amdgcn_mfma_f32_32x32x16_bf16(al1, bh, acc[1][nt], 0, 0, 0);
        }
    }

    // R4-proven epilogue: scalar fp16 stores; lanes l31=0..31 cover 32 consecutive cols
    // -> 64B-contiguous per store group.
    #pragma unroll
    for (int mt = 0; mt < 2; ++mt) {
        #pragma unroll
        for (int r = 0; r < 16; ++r) {
            int node = base + mt * 32 + (r & 3) + 8 * (r >> 2) + 4 * q8;
            if (node < Nn) {
                _Float16* yp = Y + (size_t)node * 512 + wv * 128 + l31;
                #pragma unroll
                for (int nt = 0; nt < 4; ++nt)
                    yp[nt * 32] = (_Float16)(acc[mt][nt][r] + b1v[nt]);
            }
        }
    }
}

// Edge pass: raw(e) = relu(Yr[row]+Yc[col]) . W2 + b2   (b1 pre-folded into Yr).
// Single dispatch again (instrumentation split removed). ~89 us, service-rate-bound
// (R1 depth-null, R2 sort-null); structural limit for random 512B gathers.
__global__ __launch_bounds__(256, 8)
void edge_kernel(const _Float16* __restrict__ Y, const int* __restrict__ ei,
                 const float* __restrict__ W2, const float* __restrict__ b2p,
                 float* __restrict__ out, int* __restrict__ count,
                 int* __restrict__ list, int cap, int E)
{
    const int tid  = threadIdx.x;
    const int lane = tid & 63;
    const int l31  = tid & 31;
    const int q8   = (tid & 63) >> 5;
    const int l7   = lane & 7;
    const int gw   = (blockIdx.x * 256 + tid) >> 6;
    const int nw   = (gridDim.x * 256) >> 6;

    float w2v[8];
    #pragma unroll
    for (int j = 0; j < 8; ++j) w2v[j] = W2[8 * l31 + j];
    const float b2s = b2p[0];

    const int ngrp = (E + 7) >> 3;          // 8 edges per group

    int rv = 0, cv = 0;
    int myr[4], myc[4];
    if (gw < ngrp) {
        int ib = 8 * gw + l7; if (ib >= E) ib = E - 1;
        rv = ei[ib]; cv = ei[E + ib];
    }
    #pragma unroll
    for (int k = 0; k < 4; ++k) {
        myr[k] = __shfl(rv, 2 * k + q8);    // half q8 handles edge 2k+q8
        myc[k] = __shfl(cv, 2 * k + q8);
    }

    for (int g = gw; g < ngrp; g += nw) {
        const int gn = g + nw;

        union U { uint4 u; _Float16 h[8]; };
        U yr[4], yc[4];
        #pragma unroll
        for (int k = 0; k < 4; ++k) {
            yr[k].u = *(const uint4*)(Y + (size_t)myr[k] * 512 + 8 * l31);
            yc[k].u = *(const uint4*)(Y + (size_t)myc[k] * 512 + 256 + 8 * l31);
        }

        // prefetch next group's indices (lands under the compute below)
        if (gn < ngrp) {
            int ib = 8 * gn + l7; if (ib >= E) ib = E - 1;
            rv = ei[ib]; cv = ei[E + ib];
        }

        #pragma unroll
        for (int k = 0; k < 4; ++k) {
            const int e = 8 * g + 2 * k + q8;
            float p = 0.f;
            #pragma unroll
            for (int j = 0; j < 8; ++j) {
                float h = (float)yr[k].h[j] + (float)yc[k].h[j];   // b1 already in Yr
                p += (h > 0.f ? h : 0.f) * w2v[j];
            }
            p += __shfl_xor(p, 1);  p += __shfl_xor(p, 2);  p += __shfl_xor(p, 4);
            p += __shfl_xor(p, 8);  p += __shfl_xor(p, 16);   // stays within 32-lane half
            if (l31 == 0 && e < E) {
                float raw = p + b2s;
                out[e] = (raw < T_SM) ? 0.f : raw;
                if (fabsf(raw - T_SM) < MARGIN_FAST) {
                    int pos = atomicAdd(count, 1);
                    if (pos < cap) list[pos] = e;
                }
            }
        }

        #pragma unroll
        for (int k = 0; k < 4; ++k) {
            myr[k] = __shfl(rv, 2 * k + q8);
            myc[k] = __shfl(cv, 2 * k + q8);
        }
    }
}

// ============================ FALLBACK PATH (R5, proven 475 us) ============================
__global__ __launch_bounds__(THREADS, 3)
void linkmlp_mfma(const float* __restrict__ emb, const int* __restrict__ ei,
                  const u16* __restrict__ w1t, const float* __restrict__ b1,
                  const float* __restrict__ W2, const float* __restrict__ b2p,
                  float* __restrict__ out, int* __restrict__ count,
                  int* __restrict__ list, int cap, int E)
{
    __shared__ u16 x_hi[TE * XS];
    __shared__ u16 x_lo[TE * XS];
    __shared__ float red[4][TE];
    __shared__ int s_idx[2][TE];

    const int tid  = threadIdx.x;
    const int base = blockIdx.x * TE;
    const int lane = tid & 63;
    const int wv   = tid >> 6;
    const int l31  = lane & 31;
    const int q8   = lane >> 5;
    const int ge   = tid >> 5;
    const int gseg = tid & 31;

    if (tid < TE) { int e = base + tid; s_idx[0][tid] = (e < E) ? ei[e] : 0; }
    else if (tid < 2 * TE) { int t2 = tid - TE; int e = base + t2; s_idx[1][t2] = (e < E) ? ei[E + e] : 0; }
    __syncthreads();

    float b1v[2], w2v[2];
    #pragma unroll
    for (int nt = 0; nt < 2; ++nt) {
        int c = wv * 64 + nt * 32 + l31;
        b1v[nt] = b1[c];
        w2v[nt] = W2[c];
    }
    const float b2s = b2p[0];

    f16v acc[2][2];
    #pragma unroll
    for (int mt = 0; mt < 2; ++mt)
        #pragma unroll
        for (int nt = 0; nt < 2; ++nt)
            acc[mt][nt] = (f16v)0.f;

    float4 gv[8];
    auto issue_gather = [&](int half) {
        #pragma unroll
        for (int q = 0; q < 8; ++q) {
            int node = s_idx[half][ge + 8 * q];
            gv[q] = ((const float4*)(emb + (size_t)node * 128))[gseg];
        }
    };
    auto write_gather = [&]() {
        #pragma unroll
        for (int q = 0; q < 8; ++q) {
            float4 v = gv[q];
            u16 h0 = f2bf(v.x), h1 = f2bf(v.y), h2 = f2bf(v.z), h3 = f2bf(v.w);
            u16 l0 = f2bf(v.x - bf2f(h0)), l1 = f2bf(v.y - bf2f(h1));
            u16 l2 = f2bf(v.z - bf2f(h2)), l3 = f2bf(v.w - bf2f(h3));
            int off = (ge + 8 * q) * XS + gseg * 4;
            *(uint2*)&x_hi[off] = make_uint2((unsigned)h0 | ((unsigned)h1 << 16),
                                             (unsigned)h2 | ((unsigned)h3 << 16));
            *(uint2*)&x_lo[off] = make_uint2((unsigned)l0 | ((unsigned)l1 << 16),
                                             (unsigned)l2 | ((unsigned)l3 << 16));
        }
    };

    issue_gather(0);
    write_gather();
    __syncthreads();

    #pragma unroll
    for (int half = 0; half < 2; ++half) {
        const int arow0 = l31 * XS;
        const int arow1 = (32 + l31) * XS;
        // lane-major w1t: slot(g,p) = (g*256+p)*16; p0 = wv*64+l31, p1 = p0+32; g = half*16+q8+2sl
        const u16* bbase0 = w1t + ((size_t)(half * 16 + q8) * 256 + wv * 64 + l31) * 16;
        const u16* bbase1 = bbase0 + 32 * 16;
        if (half == 0) issue_gather(1);

        auto kstep = [&](int sl) {
            const int aoff = 16 * sl + 8 * q8;
            s8v ah0 = *(const s8v*)&x_hi[arow0 + aoff];
            s8v ah1 = *(const s8v*)&x_hi[arow1 + aoff];
            s8v al0 = *(const s8v*)&x_lo[arow0 + aoff];
            s8v al1 = *(const s8v*)&x_lo[arow1 + aoff];
            const u16* bp0 = bbase0 + sl * 8192;
            const u16* bp1 = bbase1 + sl * 8192;
            s8v bh0 = *(const s8v*)bp0;  s8v bl0 = *(const s8v*)(bp0 + 8);
            s8v bh1 = *(const s8v*)bp1;  s8v bl1 = *(const s8v*)(bp1 + 8);
            acc[0][0] = __builtin_amdgcn_mfma_f32_32x32x16_bf16(ah0, bh0, acc[0][0], 0, 0, 0);
            acc[0][0] = __builtin_amdgcn_mfma_f32_32x32x16_bf16(ah0, bl0, acc[0][0], 0, 0, 0);
            acc[0][0] = __builtin_amdgcn_mfma_f32_32x32x16_bf16(al0, bh0, acc[0][0], 0, 0, 0);
            acc[1][0] = __builtin_amdgcn_mfma_f32_32x32x16_bf16(ah1, bh0, acc[1][0], 0, 0, 0);
            acc[1][0] = __builtin_amdgcn_mfma_f32_32x32x16_bf16(ah1, bl0, acc[1][0], 0, 0, 0);
            acc[1][0] = __builtin_amdgcn_mfma_f32_32x32x16_bf16(al1, bh0, acc[1][0], 0, 0, 0);
            acc[0][1] = __builtin_amdgcn_mfma_f32_32x32x16_bf16(ah0, bh1, acc[0][1], 0, 0, 0);
            acc[0][1] = __builtin_amdgcn_mfma_f32_32x32x16_bf16(ah0, bl1, acc[0][1], 0, 0, 0);
            acc[0][1] = __builtin_amdgcn_mfma_f32_32x32x16_bf16(al0, bh1, acc[0][1], 0, 0, 0);
            acc[1][1] = __builtin_amdgcn_mfma_f32_32x32x16_bf16(ah1, bh1, acc[1][1], 0, 0, 0);
            acc[1][1] = __builtin_amdgcn_mfma_f32_32x32x16_bf16(ah1, bl1, acc[1][1], 0, 0, 0);
            acc[1][1] = __builtin_amdgcn_mfma_f32_32x32x16_bf16(al1, bh1, acc[1][1], 0, 0, 0);
        };

        kstep(0); kstep(1); kstep(2); kstep(3);
        kstep(4); kstep(5); kstep(6); kstep(7);

        if (half == 0) {
            __syncthreads();
            write_gather();
            __syncthreads();
        }
    }

    #pragma unroll
    for (int mt = 0; mt < 2; ++mt) {
        #pragma unroll
        for (int r = 0; r < 16; ++r) {
            float h0 = acc[mt][0][r] + b1v[0];
            float h1 = acc[mt][1][r] + b1v[1];
            float pp = (h0 > 0.f ? h0 : 0.f) * w2v[0] + (h1 > 0.f ? h1 : 0.f) * w2v[1];
            pp += __shfl_xor(pp, 1);  pp += __shfl_xor(pp, 2);
            pp += __shfl_xor(pp, 4);  pp += __shfl_xor(pp, 8);
            pp += __shfl_xor(pp, 16);
            if (l31 == 0)
                red[wv][mt * 32 + (r & 3) + 8 * (r >> 2) + 4 * q8] = pp;
        }
    }
    __syncthreads();

    if (tid < TE) {
        int eg = base + tid;
        if (eg < E) {
            float raw = red[0][tid] + red[1][tid] + red[2][tid] + red[3][tid] + b2s;
            out[eg] = (raw < T_SM) ? 0.f : raw;
            if (fabsf(raw - T_SM) < MARGIN_FB) {
                int pos = atomicAdd(count, 1);
                if (pos < cap) list[pos] = eg;
            }
        }
    }
}

// ---- exact fp32 recompute of near-threshold edges ----
// 4 edges per wave; shared W1 stream amortized over 4 edges.
__global__ __launch_bounds__(256, 4)
void fixup_kernel(const float* __restrict__ emb, const int* __restrict__ ei,
                  const float* __restrict__ W1, const float* __restrict__ b1,
                  const float* __restrict__ W2, const float* __restrict__ b2p,
                  const int* __restrict__ count, const int* __restrict__ list,
                  float* __restrict__ out, int E, int cap)
{
    int cnt = *count; if (cnt > cap) cnt = cap;
    const int lane = threadIdx.x & 63;
    const int gw = (blockIdx.x * 256 + threadIdx.x) >> 6;
    const int nw = (gridDim.x * 256) >> 6;
    const int nbatch = (cnt + 3) >> 2;

    float b1l[4], w2l[4];
    #pragma unroll
    for (int c = 0; c < 4; ++c) {
        b1l[c] = b1[lane + 64 * c];
        w2l[c] = W2[lane + 64 * c];
    }
    const float b2s = b2p[0];

    for (int b = gw; b < nbatch; b += nw) {
        int e[4]; float4 xv[4];
        #pragma unroll
        for (int i = 0; i < 4; ++i) {
            int idx = 4 * b + i;
            e[i] = (idx < cnt) ? list[idx] : list[0];   // pad: benign duplicate recompute
            int rn = ei[e[i]], cn = ei[E + e[i]];
            const float* src = (lane < 32) ? emb + (size_t)rn * 128 + lane * 4
                                           : emb + (size_t)cn * 128 + (lane - 32) * 4;
            xv[i] = *(const float4*)src;
        }
        float hacc[4][4] = {{0.f,0.f,0.f,0.f},{0.f,0.f,0.f,0.f},
                            {0.f,0.f,0.f,0.f},{0.f,0.f,0.f,0.f}};
        for (int k0 = 0; k0 < 256; k0 += 8) {
            int sl = k0 >> 2;
            float w[8][4];
            #pragma unroll
            for (int kk = 0; kk < 8; ++kk)
                #pragma unroll
                for (int c = 0; c < 4; ++c)
                    w[kk][c] = W1[(k0 + kk) * 256 + lane + 64 * c];
            #pragma unroll
            for (int i = 0; i < 4; ++i) {
                float x[8];
                x[0] = __shfl(xv[i].x, sl);     x[1] = __shfl(xv[i].y, sl);
                x[2] = __shfl(xv[i].z, sl);     x[3] = __shfl(xv[i].w, sl);
                x[4] = __shfl(xv[i].x, sl + 1); x[5] = __shfl(xv[i].y, sl + 1);
                x[6] = __shfl(xv[i].z, sl + 1); x[7] = __shfl(xv[i].w, sl + 1);
                #pragma unroll
                for (int c = 0; c < 4; ++c) {
                    float s = hacc[i][c];
                    #pragma unroll
                    for (int kk = 0; kk < 8; ++kk)
                        s += x[kk] * w[kk][c];
                    hacc[i][c] = s;
                }
            }
        }
        #pragma unroll
        for (int i = 0; i < 4; ++i) {
            float p = 0.f;
            #pragma unroll
            for (int c = 0; c < 4; ++c) {
                float h = hacc[i][c] + b1l[c];
                p += (h > 0.f ? h : 0.f) * w2l[c];
            }
            p += __shfl_xor(p, 1);  p += __shfl_xor(p, 2);  p += __shfl_xor(p, 4);
            p += __shfl_xor(p, 8);  p += __shfl_xor(p, 16); p += __shfl_xor(p, 32);
            if (lane == 0) {
                float raw = p + b2s;
                out[e[i]] = (raw < T_SM) ? 0.f : raw;
            }
        }
    }
}

extern "C" void kernel_launch(void* const* d_in, const int* in_sizes, int n_in,
                              void* d_out, int out_size, void* d_ws, size_t ws_size,
                              hipStream_t stream) {
    const float* emb = (const float*)d_in[0];
    const int*   ei  = (const int*)  d_in[1];
    const float* W1  = (const float*)d_in[2];
    const float* b1  = (const float*)d_in[3];
    const float* W2  = (const float*)d_in[4];
    const float* b2  = (const float*)d_in[5];
    float* out = (float*)d_out;
    const int E  = out_size;
    const int Nn = in_sizes[0] / 128;

    const size_t yBytes = (size_t)Nn * 512 * sizeof(_Float16);   // 102.4 MB @ N=100000
    const size_t fastNeed = yBytes + 262144 + 64 + 65536;

    if (ws_size >= fastNeed) {
        // fast path: factorized Y-table
        _Float16* Y = (_Float16*)d_ws;
        u16* w1t   = (u16*)((char*)d_ws + yBytes);
        int* count = (int*)((char*)d_ws + yBytes + 262144);
        int* list  = (int*)((char*)d_ws + yBytes + 262208);
        int cap = (int)((ws_size - (yBytes + 262208)) / 4);
        if (cap > E) cap = E;

        hipLaunchKernelGGL(prep_kernel, dim3(256), dim3(256), 0, stream, W1, w1t, count);
        hipLaunchKernelGGL(gemm_y_kernel, dim3((Nn + TE - 1) / TE), dim3(THREADS), 0, stream,
                           emb, w1t, b1, Y, Nn);
        hipLaunchKernelGGL(edge_kernel, dim3(4096), dim3(256), 0, stream,
                           Y, ei, W2, b2, out, count, list, cap, E);
        hipLaunchKernelGGL(fixup_kernel, dim3(1024), dim3(256), 0, stream,
                           emb, ei, W1, b1, W2, b2, count, list, out, E, cap);
    } else {
        // fallback: R5 fused edge-GEMM (proven)
        u16* w1t   = (u16*)d_ws;
        int* count = (int*)((char*)d_ws + 262144);
        int* list  = (int*)((char*)d_ws + 262208);
        long avail = (long)ws_size - 262208;
        int cap = (avail > 4) ? (int)(avail / 4) : 0;
        if (cap > E) cap = E;

        hipLaunchKernelGGL(prep_kernel, dim3(256), dim3(256), 0, stream, W1, w1t, count);
        hipLaunchKernelGGL(linkmlp_mfma, dim3((E + TE - 1) / TE), dim3(THREADS), 0, stream,
                           emb, ei, w1t, b1, W2, b2, out, count, list, cap, E);
        hipLaunchKernelGGL(fixup_kernel, dim3(128), dim3(256), 0, stream,
                           emb, ei, W1, b1, W2, b2, count, list, out, E, cap);
    }
}

// Round 10
// 249.673 us; speedup vs baseline: 1.0686x; 1.0040x over previous
//
#include <hip/hip_runtime.h>

#define TE 64
#define THREADS 256
#define XS 136         // u16 LDS stride per row: 128 + 8 pad (conflict-free)
#define T_SM 0.05f
#define MARGIN_FAST 2.5e-3f  // fp16-Y raw err max ~1.7e-3 (measured 5sigma); 1.5x headroom
#define MARGIN_FB   1e-3f

typedef short s8v __attribute__((ext_vector_type(8)));    // 8 bf16 = 4 VGPRs (MFMA A/B frag)
typedef float f16v __attribute__((ext_vector_type(16)));  // 32x32 C/D frag
typedef unsigned short u16;

__device__ __forceinline__ u16 f2bf(float x) {            // fp32 -> bf16 RNE
    union { float f; unsigned u; } v; v.f = x;
    return (u16)((v.u + 0x7FFFu + ((v.u >> 16) & 1u)) >> 16);
}
__device__ __forceinline__ float bf2f(u16 h) {
    union { unsigned u; float f; } v; v.u = ((unsigned)h) << 16;
    return v.f;
}

// ---- W1 [256,256] f32 -> bf16 hi/lo, LANE-MAJOR B-tile layout ----
// slot(g,p) = (g*256 + p)*16, hi at j=0..7, lo at j=8..15  (g = k>>3, p = out col).
// A B-frag load (fixed g, lanes p..p+31) is lane-stride 32 B -> contiguous 1 KB.
__global__ void prep_kernel(const float* __restrict__ W1, u16* __restrict__ w1t,
                            int* __restrict__ count) {
    int t = blockIdx.x * 256 + threadIdx.x;
    if (t == 0) *count = 0;
    if (t < 65536) {
        int n = t & 255, k = t >> 8;
        float w = W1[k * 256 + n];
        u16 h = f2bf(w);
        u16 l = f2bf(w - bf2f(h));
        int g = k >> 3, j = k & 7;
        int slot = (g * 256 + n) * 16;
        w1t[slot + j] = h;
        w1t[slot + j + 8] = l;
    }
}

// ============================ FAST PATH ============================
// Dense GEMM: Y[n][0:256]=emb[n]@W1[0:128,:]+b1 (b1 FOLDED into Yr half),
//             Y[n][256:512]=emb[n]@W1[128:,:].
// R10: PERMUTED-Y epilogue. The edge pass is a permutation-invariant reduction, so Y's
// column order is free. Storage col (within a wave's 128-col block) = l31*4+nt
// (orig = nt*32+l31): each lane owns 4 consecutive fp16 per row -> one uint2 store.
// 32x8B stores/lane vs R4's 128x2B (store-issue-bound, 65us) or R5's LDS restage
// (bank conflicts, 80us). Edge kernel permutes its one-time W2 gather to match.
__global__ __launch_bounds__(THREADS, 2)
void gemm_y_kernel(const float* __restrict__ emb, const u16* __restrict__ w1t,
                   const float* __restrict__ b1, _Float16* __restrict__ Y, int Nn)
{
    __shared__ u16 x_hi[TE * XS];
    __shared__ u16 x_lo[TE * XS];

    const int tid  = threadIdx.x;
    const int base = blockIdx.x * TE;
    const int lane = tid & 63;
    const int wv   = tid >> 6;
    const int l31  = lane & 31;
    const int q8   = lane >> 5;
    const int ge   = tid >> 5;
    const int gseg = tid & 31;

    #pragma unroll
    for (int q = 0; q < 8; ++q) {
        int node = base + ge + 8 * q;
        if (node >= Nn) node = Nn - 1;
        float4 v = ((const float4*)(emb + (size_t)node * 128))[gseg];
        u16 h0 = f2bf(v.x), h1 = f2bf(v.y), h2 = f2bf(v.z), h3 = f2bf(v.w);
        u16 l0 = f2bf(v.x - bf2f(h0)), l1 = f2bf(v.y - bf2f(h1));
        u16 l2 = f2bf(v.z - bf2f(h2)), l3 = f2bf(v.w - bf2f(h3));
        int off = (ge + 8 * q) * XS + gseg * 4;
        *(uint2*)&x_hi[off] = make_uint2((unsigned)h0 | ((unsigned)h1 << 16),
                                         (unsigned)h2 | ((unsigned)h3 << 16));
        *(uint2*)&x_lo[off] = make_uint2((unsigned)l0 | ((unsigned)l1 << 16),
                                         (unsigned)l2 | ((unsigned)l3 << 16));
    }
    __syncthreads();

    f16v acc[2][4];
    #pragma unroll
    for (int mt = 0; mt < 2; ++mt)
        #pragma unroll
        for (int nt = 0; nt < 4; ++nt)
            acc[mt][nt] = (f16v)0.f;

    const int arow0 = l31 * XS;
    const int arow1 = (32 + l31) * XS;
    const u16* bb[4];
    float b1v[4];
    #pragma unroll
    for (int nt = 0; nt < 4; ++nt) {
        int ncol = wv * 128 + nt * 32 + l31;          // 0..511
        int p = ncol & 255;
        int gbase = (ncol >> 8) * 16;                 // Yr: g0..15, Yc: g16..31
        bb[nt] = w1t + ((size_t)(gbase + q8) * 256 + p) * 16;
        b1v[nt] = (ncol < 256) ? b1[ncol] : 0.f;      // fold b1 into Yr half only
    }

    #pragma unroll
    for (int sl = 0; sl < 8; ++sl) {                  // K=128 in 8 ksteps of 16
        const int aoff = 16 * sl + 8 * q8;
        s8v ah0 = *(const s8v*)&x_hi[arow0 + aoff];
        s8v ah1 = *(const s8v*)&x_hi[arow1 + aoff];
        s8v al0 = *(const s8v*)&x_lo[arow0 + aoff];
        s8v al1 = *(const s8v*)&x_lo[arow1 + aoff];
        #pragma unroll
        for (int nt = 0; nt < 4; ++nt) {
            const u16* bp = bb[nt] + sl * 8192;       // g advances by 2 per sl
            s8v bh = *(const s8v*)bp;
            s8v bl = *(const s8v*)(bp + 8);
            acc[0][nt] = __builtin_amdgcn_mfma_f32_32x32x16_bf16(ah0, bh, acc[0][nt], 0, 0, 0);
            acc[0][nt] = __builtin_amdgcn_mfma_f32_32x32x16_bf16(ah0, bl, acc[0][nt], 0, 0, 0);
            acc[0][nt] = __builtin_amdgcn_mfma_f32_32x32x16_bf16(al0, bh, acc[0][nt], 0, 0, 0);
            acc[1][nt] = __builtin_amdgcn_mfma_f32_32x32x16_bf16(ah1, bh, acc[1][nt], 0, 0, 0);
            acc[1][nt] = __builtin_amdgcn_mfma_f32_32x32x16_bf16(ah1, bl, acc[1][nt], 0, 0, 0);
            acc[1][nt] = __builtin_amdgcn_mfma_f32_32x32x16_bf16(al1, bh, acc[1][nt], 0, 0, 0);
        }
    }

    // permuted-Y epilogue: lane packs its 4 nt-values (one row) into uint2.
    // Lanes 0..31 write consecutive 8B -> 256B contiguous per (mt,r) store group.
    #pragma unroll
    for (int mt = 0; mt < 2; ++mt) {
        #pragma unroll
        for (int r = 0; r < 16; ++r) {
            int node = base + mt * 32 + (r & 3) + 8 * (r >> 2) + 4 * q8;
            if (node < Nn) {
                union { uint2 u; _Float16 h[4]; } pk;
                #pragma unroll
                for (int nt = 0; nt < 4; ++nt)
                    pk.h[nt] = (_Float16)(acc[mt][nt][r] + b1v[nt]);
                *(uint2*)(Y + (size_t)node * 512 + wv * 128 + l31 * 4) = pk.u;
            }
        }
    }
}

// Edge pass: raw(e) = relu(Yr[row]+Yc[col]) . W2 + b2   (b1 pre-folded into Yr).
// Y columns are stored PERMUTED (see gemm epilogue): within each 128-col block wb,
// storage s128 = l31*4+nt <-> orig = nt*32+l31. The reduction is order-invariant, so
// only the one-time W2 register gather needs the inverse map:
//   orig(s) = wb*128 + (s128&3)*32 + (s128>>2),  s = 8*l31+j, wb = l31>>4.
__global__ __launch_bounds__(256, 8)
void edge_kernel(const _Float16* __restrict__ Y, const int* __restrict__ ei,
                 const float* __restrict__ W2, const float* __restrict__ b2p,
                 float* __restrict__ out, int* __restrict__ count,
                 int* __restrict__ list, int cap, int E)
{
    const int tid  = threadIdx.x;
    const int lane = tid & 63;
    const int l31  = tid & 31;
    const int q8   = (tid & 63) >> 5;
    const int l7   = lane & 7;
    const int gw   = (blockIdx.x * 256 + tid) >> 6;
    const int nw   = (gridDim.x * 256) >> 6;

    const int wb = l31 >> 4;
    const int lq = l31 & 15;
    float w2v[8];
    #pragma unroll
    for (int j = 0; j < 8; ++j)
        w2v[j] = W2[wb * 128 + (j & 3) * 32 + 2 * lq + (j >> 2)];
    const float b2s = b2p[0];

    const int ngrp = (E + 7) >> 3;          // 8 edges per group

    int rv = 0, cv = 0;
    int myr[4], myc[4];
    if (gw < ngrp) {
        int ib = 8 * gw + l7; if (ib >= E) ib = E - 1;
        rv = ei[ib]; cv = ei[E + ib];
    }
    #pragma unroll
    for (int k = 0; k < 4; ++k) {
        myr[k] = __shfl(rv, 2 * k + q8);    // half q8 handles edge 2k+q8
        myc[k] = __shfl(cv, 2 * k + q8);
    }

    for (int g = gw; g < ngrp; g += nw) {
        const int gn = g + nw;

        union U { uint4 u; _Float16 h[8]; };
        U yr[4], yc[4];
        #pragma unroll
        for (int k = 0; k < 4; ++k) {
            yr[k].u = *(const uint4*)(Y + (size_t)myr[k] * 512 + 8 * l31);
            yc[k].u = *(const uint4*)(Y + (size_t)myc[k] * 512 + 256 + 8 * l31);
        }

        // prefetch next group's indices (lands under the compute below)
        if (gn < ngrp) {
            int ib = 8 * gn + l7; if (ib >= E) ib = E - 1;
            rv = ei[ib]; cv = ei[E + ib];
        }

        #pragma unroll
        for (int k = 0; k < 4; ++k) {
            const int e = 8 * g + 2 * k + q8;
            float p = 0.f;
            #pragma unroll
            for (int j = 0; j < 8; ++j) {
                float h = (float)yr[k].h[j] + (float)yc[k].h[j];   // b1 already in Yr
                p += (h > 0.f ? h : 0.f) * w2v[j];
            }
            p += __shfl_xor(p, 1);  p += __shfl_xor(p, 2);  p += __shfl_xor(p, 4);
            p += __shfl_xor(p, 8);  p += __shfl_xor(p, 16);   // stays within 32-lane half
            if (l31 == 0 && e < E) {
                float raw = p + b2s;
                out[e] = (raw < T_SM) ? 0.f : raw;
                if (fabsf(raw - T_SM) < MARGIN_FAST) {
                    int pos = atomicAdd(count, 1);
                    if (pos < cap) list[pos] = e;
                }
            }
        }

        #pragma unroll
        for (int k = 0; k < 4; ++k) {
            myr[k] = __shfl(rv, 2 * k + q8);
            myc[k] = __shfl(cv, 2 * k + q8);
        }
    }
}

// ============================ FALLBACK PATH (R5, proven 475 us) ============================
__global__ __launch_bounds__(THREADS, 3)
void linkmlp_mfma(const float* __restrict__ emb, const int* __restrict__ ei,
                  const u16* __restrict__ w1t, const float* __restrict__ b1,
                  const float* __restrict__ W2, const float* __restrict__ b2p,
                  float* __restrict__ out, int* __restrict__ count,
                  int* __restrict__ list, int cap, int E)
{
    __shared__ u16 x_hi[TE * XS];
    __shared__ u16 x_lo[TE * XS];
    __shared__ float red[4][TE];
    __shared__ int s_idx[2][TE];

    const int tid  = threadIdx.x;
    const int base = blockIdx.x * TE;
    const int lane = tid & 63;
    const int wv   = tid >> 6;
    const int l31  = lane & 31;
    const int q8   = lane >> 5;
    const int ge   = tid >> 5;
    const int gseg = tid & 31;

    if (tid < TE) { int e = base + tid; s_idx[0][tid] = (e < E) ? ei[e] : 0; }
    else if (tid < 2 * TE) { int t2 = tid - TE; int e = base + t2; s_idx[1][t2] = (e < E) ? ei[E + e] : 0; }
    __syncthreads();

    float b1v[2], w2v[2];
    #pragma unroll
    for (int nt = 0; nt < 2; ++nt) {
        int c = wv * 64 + nt * 32 + l31;
        b1v[nt] = b1[c];
        w2v[nt] = W2[c];
    }
    const float b2s = b2p[0];

    f16v acc[2][2];
    #pragma unroll
    for (int mt = 0; mt < 2; ++mt)
        #pragma unroll
        for (int nt = 0; nt < 2; ++nt)
            acc[mt][nt] = (f16v)0.f;

    float4 gv[8];
    auto issue_gather = [&](int half) {
        #pragma unroll
        for (int q = 0; q < 8; ++q) {
            int node = s_idx[half][ge + 8 * q];
            gv[q] = ((const float4*)(emb + (size_t)node * 128))[gseg];
        }
    };
    auto write_gather = [&]() {
        #pragma unroll
        for (int q = 0; q < 8; ++q) {
            float4 v = gv[q];
            u16 h0 = f2bf(v.x), h1 = f2bf(v.y), h2 = f2bf(v.z), h3 = f2bf(v.w);
            u16 l0 = f2bf(v.x - bf2f(h0)), l1 = f2bf(v.y - bf2f(h1));
            u16 l2 = f2bf(v.z - bf2f(h2)), l3 = f2bf(v.w - bf2f(h3));
            int off = (ge + 8 * q) * XS + gseg * 4;
            *(uint2*)&x_hi[off] = make_uint2((unsigned)h0 | ((unsigned)h1 << 16),
                                             (unsigned)h2 | ((unsigned)h3 << 16));
            *(uint2*)&x_lo[off] = make_uint2((unsigned)l0 | ((unsigned)l1 << 16),
                                             (unsigned)l2 | ((unsigned)l3 << 16));
        }
    };

    issue_gather(0);
    write_gather();
    __syncthreads();

    #pragma unroll
    for (int half = 0; half < 2; ++half) {
        const int arow0 = l31 * XS;
        const int arow1 = (32 + l31) * XS;
        // lane-major w1t: slot(g,p) = (g*256+p)*16; p0 = wv*64+l31, p1 = p0+32; g = half*16+q8+2sl
        const u16* bbase0 = w1t + ((size_t)(half * 16 + q8) * 256 + wv * 64 + l31) * 16;
        const u16* bbase1 = bbase0 + 32 * 16;
        if (half == 0) issue_gather(1);

        auto kstep = [&](int sl) {
            const int aoff = 16 * sl + 8 * q8;
            s8v ah0 = *(const s8v*)&x_hi[arow0 + aoff];
            s8v ah1 = *(const s8v*)&x_hi[arow1 + aoff];
            s8v al0 = *(const s8v*)&x_lo[arow0 + aoff];
            s8v al1 = *(const s8v*)&x_lo[arow1 + aoff];
            const u16* bp0 = bbase0 + sl * 8192;
            const u16* bp1 = bbase1 + sl * 8192;
            s8v bh0 = *(const s8v*)bp0;  s8v bl0 = *(const s8v*)(bp0 + 8);
            s8v bh1 = *(const s8v*)bp1;  s8v bl1 = *(const s8v*)(bp1 + 8);
            acc[0][0] = __builtin_amdgcn_mfma_f32_32x32x16_bf16(ah0, bh0, acc[0][0], 0, 0, 0);
            acc[0][0] = __builtin_amdgcn_mfma_f32_32x32x16_bf16(ah0, bl0, acc[0][0], 0, 0, 0);
            acc[0][0] = __builtin_amdgcn_mfma_f32_32x32x16_bf16(al0, bh0, acc[0][0], 0, 0, 0);
            acc[1][0] = __builtin_amdgcn_mfma_f32_32x32x16_bf16(ah1, bh0, acc[1][0], 0, 0, 0);
            acc[1][0] = __builtin_amdgcn_mfma_f32_32x32x16_bf16(ah1, bl0, acc[1][0], 0, 0, 0);
            acc[1][0] = __builtin_amdgcn_mfma_f32_32x32x16_bf16(al1, bh0, acc[1][0], 0, 0, 0);
            acc[0][1] = __builtin_amdgcn_mfma_f32_32x32x16_bf16(ah0, bh1, acc[0][1], 0, 0, 0);
            acc[0][1] = __builtin_amdgcn_mfma_f32_32x32x16_bf16(ah0, bl1, acc[0][1], 0, 0, 0);
            acc[0][1] = __builtin_amdgcn_mfma_f32_32x32x16_bf16(al0, bh1, acc[0][1], 0, 0, 0);
            acc[1][1] = __builtin_amdgcn_mfma_f32_32x32x16_bf16(ah1, bh1, acc[1][1], 0, 0, 0);
            acc[1][1] = __builtin_amdgcn_mfma_f32_32x32x16_bf16(ah1, bl1, acc[1][1], 0, 0, 0);
            acc[1][1] = __builtin_amdgcn_mfma_f32_32x32x16_bf16(al1, bh1, acc[1][1], 0, 0, 0);
        };

        kstep(0); kstep(1); kstep(2); kstep(3);
        kstep(4); kstep(5); kstep(6); kstep(7);

        if (half == 0) {
            __syncthreads();
            write_gather();
            __syncthreads();
        }
    }

    #pragma unroll
    for (int mt = 0; mt < 2; ++mt) {
        #pragma unroll
        for (int r = 0; r < 16; ++r) {
            float h0 = acc[mt][0][r] + b1v[0];
            float h1 = acc[mt][1][r] + b1v[1];
            float pp = (h0 > 0.f ? h0 : 0.f) * w2v[0] + (h1 > 0.f ? h1 : 0.f) * w2v[1];
            pp += __shfl_xor(pp, 1);  pp += __shfl_xor(pp, 2);
            pp += __shfl_xor(pp, 4);  pp += __shfl_xor(pp, 8);
            pp += __shfl_xor(pp, 16);
            if (l31 == 0)
                red[wv][mt * 32 + (r & 3) + 8 * (r >> 2) + 4 * q8] = pp;
        }
    }
    __syncthreads();

    if (tid < TE) {
        int eg = base + tid;
        if (eg < E) {
            float raw = red[0][tid] + red[1][tid] + red[2][tid] + red[3][tid] + b2s;
            out[eg] = (raw < T_SM) ? 0.f : raw;
            if (fabsf(raw - T_SM) < MARGIN_FB) {
                int pos = atomicAdd(count, 1);
                if (pos < cap) list[pos] = eg;
            }
        }
    }
}

// ---- exact fp32 recompute of near-threshold edges ----
// 4 edges per wave; shared W1 stream amortized over 4 edges.
__global__ __launch_bounds__(256, 4)
void fixup_kernel(const float* __restrict__ emb, const int* __restrict__ ei,
                  const float* __restrict__ W1, const float* __restrict__ b1,
                  const float* __restrict__ W2, const float* __restrict__ b2p,
                  const int* __restrict__ count, const int* __restrict__ list,
                  float* __restrict__ out, int E, int cap)
{
    int cnt = *count; if (cnt > cap) cnt = cap;
    const int lane = threadIdx.x & 63;
    const int gw = (blockIdx.x * 256 + threadIdx.x) >> 6;
    const int nw = (gridDim.x * 256) >> 6;
    const int nbatch = (cnt + 3) >> 2;

    float b1l[4], w2l[4];
    #pragma unroll
    for (int c = 0; c < 4; ++c) {
        b1l[c] = b1[lane + 64 * c];
        w2l[c] = W2[lane + 64 * c];
    }
    const float b2s = b2p[0];

    for (int b = gw; b < nbatch; b += nw) {
        int e[4]; float4 xv[4];
        #pragma unroll
        for (int i = 0; i < 4; ++i) {
            int idx = 4 * b + i;
            e[i] = (idx < cnt) ? list[idx] : list[0];   // pad: benign duplicate recompute
            int rn = ei[e[i]], cn = ei[E + e[i]];
            const float* src = (lane < 32) ? emb + (size_t)rn * 128 + lane * 4
                                           : emb + (size_t)cn * 128 + (lane - 32) * 4;
            xv[i] = *(const float4*)src;
        }
        float hacc[4][4] = {{0.f,0.f,0.f,0.f},{0.f,0.f,0.f,0.f},
                            {0.f,0.f,0.f,0.f},{0.f,0.f,0.f,0.f}};
        for (int k0 = 0; k0 < 256; k0 += 8) {
            int sl = k0 >> 2;
            float w[8][4];
            #pragma unroll
            for (int kk = 0; kk < 8; ++kk)
                #pragma unroll
                for (int c = 0; c < 4; ++c)
                    w[kk][c] = W1[(k0 + kk) * 256 + lane + 64 * c];
            #pragma unroll
            for (int i = 0; i < 4; ++i) {
                float x[8];
                x[0] = __shfl(xv[i].x, sl);     x[1] = __shfl(xv[i].y, sl);
                x[2] = __shfl(xv[i].z, sl);     x[3] = __shfl(xv[i].w, sl);
                x[4] = __shfl(xv[i].x, sl + 1); x[5] = __shfl(xv[i].y, sl + 1);
                x[6] = __shfl(xv[i].z, sl + 1); x[7] = __shfl(xv[i].w, sl + 1);
                #pragma unroll
                for (int c = 0; c < 4; ++c) {
                    float s = hacc[i][c];
                    #pragma unroll
                    for (int kk = 0; kk < 8; ++kk)
                        s += x[kk] * w[kk][c];
                    hacc[i][c] = s;
                }
            }
        }
        #pragma unroll
        for (int i = 0; i < 4; ++i) {
            float p = 0.f;
            #pragma unroll
            for (int c = 0; c < 4; ++c) {
                float h = hacc[i][c] + b1l[c];
                p += (h > 0.f ? h : 0.f) * w2l[c];
            }
            p += __shfl_xor(p, 1);  p += __shfl_xor(p, 2);  p += __shfl_xor(p, 4);
            p += __shfl_xor(p, 8);  p += __shfl_xor(p, 16); p += __shfl_xor(p, 32);
            if (lane == 0) {
                float raw = p + b2s;
                out[e[i]] = (raw < T_SM) ? 0.f : raw;
            }
        }
    }
}

extern "C" void kernel_launch(void* const* d_in, const int* in_sizes, int n_in,
                              void* d_out, int out_size, void* d_ws, size_t ws_size,
                              hipStream_t stream) {
    const float* emb = (const float*)d_in[0];
    const int*   ei  = (const int*)  d_in[1];
    const float* W1  = (const float*)d_in[2];
    const float* b1  = (const float*)d_in[3];
    const float* W2  = (const float*)d_in[4];
    const float* b2  = (const float*)d_in[5];
    float* out = (float*)d_out;
    const int E  = out_size;
    const int Nn = in_sizes[0] / 128;

    const size_t yBytes = (size_t)Nn * 512 * sizeof(_Float16);   // 102.4 MB @ N=100000
    const size_t fastNeed = yBytes + 262144 + 64 + 65536;

    if (ws_size >= fastNeed) {
        // fast path: factorized Y-table
        _Float16* Y = (_Float16*)d_ws;
        u16* w1t   = (u16*)((char*)d_ws + yBytes);
        int* count = (int*)((char*)d_ws + yBytes + 262144);
        int* list  = (int*)((char*)d_ws + yBytes + 262208);
        int cap = (int)((ws_size - (yBytes + 262208)) / 4);
        if (cap > E) cap = E;

        hipLaunchKernelGGL(prep_kernel, dim3(256), dim3(256), 0, stream, W1, w1t, count);
        hipLaunchKernelGGL(gemm_y_kernel, dim3((Nn + TE - 1) / TE), dim3(THREADS), 0, stream,
                           emb, w1t, b1, Y, Nn);
        hipLaunchKernelGGL(edge_kernel, dim3(4096), dim3(256), 0, stream,
                           Y, ei, W2, b2, out, count, list, cap, E);
        hipLaunchKernelGGL(fixup_kernel, dim3(1024), dim3(256), 0, stream,
                           emb, ei, W1, b1, W2, b2, count, list, out, E, cap);
    } else {
        // fallback: R5 fused edge-GEMM (proven)
        u16* w1t   = (u16*)d_ws;
        int* count = (int*)((char*)d_ws + 262144);
        int* list  = (int*)((char*)d_ws + 262208);
        long avail = (long)ws_size - 262208;
        int cap = (avail > 4) ? (int)(avail / 4) : 0;
        if (cap > E) cap = E;

        hipLaunchKernelGGL(prep_kernel, dim3(256), dim3(256), 0, stream, W1, w1t, count);
        hipLaunchKernelGGL(linkmlp_mfma, dim3((E + TE - 1) / TE), dim3(THREADS), 0, stream,
                           emb, ei, w1t, b1, W2, b2, out, count, list, cap, E);
        hipLaunchKernelGGL(fixup_kernel, dim3(128), dim3(256), 0, stream,
                           emb, ei, W1, b1, W2, b2, count, list, out, E, cap);
    }
}